// Round 10
// baseline (243.254 us; speedup 1.0000x reference)
//
#include <hip/hip_runtime.h>

#define C 64
#define RMAX 50
#define LEAKY 0.2f
#define CAP 48   // bucket slots per head; 48*4B=192B (16B-aligned for int4 reads)

__device__ __forceinline__ float bf2f(unsigned short u) {
  return __uint_as_float(((unsigned)u) << 16);
}
__device__ __forceinline__ unsigned short f2bf(float x) {
  unsigned u = __float_as_uint(x);
  return (unsigned short)((u + 0x7FFFu + ((u >> 16) & 1u)) >> 16);  // RNE
}

// ---- in-wave dtype self-detection ----
__device__ __forceinline__ int wave_isbf(const void* ent) {
  const unsigned* w = (const unsigned*)ent;
  const int lane = threadIdx.x & 63;
  int ok = 0;
#pragma unroll
  for (int i = 0; i < 4; ++i) {
    unsigned lo = w[lane + 64 * i] & 0xFFFFu;
    float a = fabsf(__uint_as_float(lo << 16));
    ok += (lo == 0u || (a >= 1e-9f && a <= 1e9f)) ? 1 : 0;
  }
#pragma unroll
  for (int d = 1; d < 64; d <<= 1) ok += __shfl_xor(ok, d, 64);
  return ok >= 224;
}
__device__ __forceinline__ int wave_is64(const int* p) {
  const int lane = threadIdx.x & 63;
  int z = (p[2 * lane + 1] == 0) ? 1 : 0;
#pragma unroll
  for (int d = 1; d < 64; d <<= 1) z += __shfl_xor(z, d, 64);
  return z >= 62;
}
__device__ __forceinline__ float loadF(const void* p, int i, int isbf) {
  return isbf ? bf2f(((const unsigned short*)p)[i]) : ((const float*)p)[i];
}

// ---- precompute U[r]=W1^T rel_r, V[r]=W2^T rel_r, c[r]=rel_r . b ----
__global__ void uvc_kernel(const void* __restrict__ rel,
                           const void* __restrict__ fcw,
                           const void* __restrict__ fcb,
                           float* __restrict__ U, float* __restrict__ V,
                           float* __restrict__ cvec) {
  const int isbf = wave_isbf(rel);
  const int r = blockIdx.x;
  const int i = threadIdx.x;  // 0..127
  float acc = 0.f;
  for (int o = 0; o < C; ++o)
    acc += loadF(rel, r * C + o, isbf) * loadF(fcw, o * (2 * C) + i, isbf);
  if (i < C) U[r * C + i] = acc;
  else       V[r * C + (i - C)] = acc;
  if (i < C) {
    float p = loadF(rel, r * C + i, isbf) * loadF(fcb, i, isbf);
#pragma unroll
    for (int d = 1; d < 64; d <<= 1) p += __shfl_xor(p, d, 64);
    if (i == 0) cvec[r] = p;
  }
}

// ---- ent -> bf16 canonical copy ----
__global__ void conv_kernel(const void* __restrict__ ent, unsigned* __restrict__ dst,
                            int n8) {
  const int isbf = wave_isbf(ent);
  int i = blockIdx.x * blockDim.x + threadIdx.x;
  if (i >= n8) return;
  uint4 o;
  if (isbf) {
    o = ((const uint4*)ent)[i];
  } else {
    const float4* q = (const float4*)ent;
    float4 a = q[2 * i], b = q[2 * i + 1];
    o.x = (unsigned)f2bf(a.x) | ((unsigned)f2bf(a.y) << 16);
    o.y = (unsigned)f2bf(a.z) | ((unsigned)f2bf(a.w) << 16);
    o.z = (unsigned)f2bf(b.x) | ((unsigned)f2bf(b.y) << 16);
    o.w = (unsigned)f2bf(b.z) | ((unsigned)f2bf(b.w) << 16);
  }
  ((uint4*)dst)[i] = o;
}

// ---- direct bucket fill (fallback tier) ----
__global__ void fillb_kernel(const int* __restrict__ eidx, const int* __restrict__ etype,
                             int* __restrict__ cnt, int* __restrict__ packed,
                             int E, int N, int Rc) {
  const int is64 = wave_is64(eidx);
  const int et64 = wave_is64(etype);
  const int base = (blockIdx.x * blockDim.x + threadIdx.x) * 4;
  int h[4], t[4], r[4];
#pragma unroll
  for (int k = 0; k < 4; ++k) {
    const int e = base + k;
    if (e < E) {
      h[k] = is64 ? eidx[2 * e] : eidx[e];
      t[k] = is64 ? eidx[2 * E + 2 * e] : eidx[E + e];
      r[k] = et64 ? etype[2 * e] : etype[e];
    }
  }
  int pos[4];
#pragma unroll
  for (int k = 0; k < 4; ++k) {
    const int e = base + k;
    if (e < E) {
      if ((unsigned)h[k] >= (unsigned)N) h[k] = 0;
      pos[k] = atomicAdd(&cnt[h[k]], 1);
    }
  }
#pragma unroll
  for (int k = 0; k < 4; ++k) {
    const int e = base + k;
    if (e < E && pos[k] < CAP) {
      int tt = t[k]; if ((unsigned)tt >= (unsigned)N) tt = 0;
      int rr = r[k]; if ((unsigned)rr >= (unsigned)Rc) rr = 0;
      packed[h[k] * CAP + pos[k]] = tt | (rr << 20);
    }
  }
}

// ---- fill pass A: coarse-bucket scatter. 256 thr x 4 edges = 1024 edges/block.
// bcnt padded: counter b at bcnt[b*16] (own 64B line). ----
__global__ void fillA_kernel(const int* __restrict__ eidx, const int* __restrict__ etype,
                             int* __restrict__ bcnt, int2* __restrict__ bbuf,
                             int E, int N, int Rc, int shift, int nbuck, int bcap) {
  __shared__ int lh[256];
  __shared__ int gbase[256];
  const int is64 = wave_is64(eidx);
  const int et64 = wave_is64(etype);
  const int tid = threadIdx.x;
  if (tid < 256) lh[tid] = 0;
  const int eBase = blockIdx.x * 1024;
  int h[4], tr[4], bk[4], lp[4], ok[4];
  __syncthreads();
#pragma unroll
  for (int k = 0; k < 4; ++k) {
    const int e = eBase + k * 256 + tid;
    ok[k] = (e < E);
    if (ok[k]) {
      int hh = is64 ? eidx[2 * e] : eidx[e];
      int tt = is64 ? eidx[2 * E + 2 * e] : eidx[E + e];
      int rr = et64 ? etype[2 * e] : etype[e];
      if ((unsigned)hh >= (unsigned)N) hh = 0;
      if ((unsigned)tt >= (unsigned)N) tt = 0;
      if ((unsigned)rr >= (unsigned)Rc) rr = 0;
      h[k] = hh; tr[k] = tt | (rr << 20);
      bk[k] = hh >> shift;
      lp[k] = atomicAdd(&lh[bk[k]], 1);
    }
  }
  __syncthreads();
  if (tid < nbuck) gbase[tid] = lh[tid] ? atomicAdd(&bcnt[tid * 16], lh[tid]) : 0;
  __syncthreads();
#pragma unroll
  for (int k = 0; k < 4; ++k) {
    if (ok[k]) {
      int posb = gbase[bk[k]] + lp[k];
      if (posb < bcap) bbuf[(size_t)bk[k] * bcap + posb] = make_int2(h[k], tr[k]);
    }
  }
}

// ---- fill pass B: 4 blocks per bucket (occupancy); cnt/packed region L2-local ----
__global__ void fillB_kernel(const int* __restrict__ bcnt, const int2* __restrict__ bbuf,
                             int* __restrict__ cnt, int* __restrict__ packed,
                             int N, int bcap) {
  const int b = blockIdx.x >> 2;
  const int sub = blockIdx.x & 3;
  int bc = bcnt[b * 16]; if (bc > bcap) bc = bcap;
  const int2* src = &bbuf[(size_t)b * bcap];
  for (int k = sub * 256 + threadIdx.x; k < bc; k += 1024) {
    int2 e = src[k];
    int h = e.x; if ((unsigned)h >= (unsigned)N) h = 0;
    int pos = atomicAdd(&cnt[h], 1);
    if (pos < CAP) packed[h * CAP + pos] = e.y;
  }
}

// ---- degree histogram over cnt (hist padded: bin k at hist[k*16]) ----
__global__ void histo_kernel(const int* __restrict__ cnt, int* __restrict__ hist, int N) {
  __shared__ int histS[65];
  const int tid = threadIdx.x;
  for (int k = tid; k < 65; k += 1024) histS[k] = 0;
  __syncthreads();
  const int i = blockIdx.x * 1024 + tid;
  if (i < N) {
    int b = cnt[i]; if (b > 64) b = 64;
    atomicAdd(&histS[b], 1);
  }
  __syncthreads();
  for (int k = tid; k < 65; k += 1024)
    if (histS[k]) atomicAdd(&hist[k * 16], histS[k]);
}

// ---- degree-sorted order, DESCENDING (LPT: big blocks first, small pack the tail) ----
__global__ void order_kernel(const int* __restrict__ cnt, const int* __restrict__ hist,
                             int* __restrict__ bincur, int* __restrict__ order, int N) {
  __shared__ int binstart[66];
  __shared__ int lh[65];
  __shared__ int lbase[65];
  const int tid = threadIdx.x;
  for (int k = tid; k < 65; k += 1024) { binstart[k] = hist[k * 16]; lh[k] = 0; }
  __syncthreads();
  if (tid == 0) {
    int run = 0;
    for (int k = 64; k >= 0; --k) { int t = binstart[k]; binstart[k] = run; run += t; }
    binstart[65] = run;
  }
  __syncthreads();
  const int i = blockIdx.x * 1024 + tid;
  int b = 0, lpos = 0;
  if (i < N) {
    b = cnt[i]; if (b > 64) b = 64;
    lpos = atomicAdd(&lh[b], 1);
  }
  __syncthreads();
  if (tid < 65) lbase[tid] = lh[tid] ? atomicAdd(&bincur[tid * 16], lh[tid]) : 0;
  __syncthreads();
  if (i < N) {
    int dst = binstart[b] + lbase[b] + lpos;
    if ((unsigned)dst < (unsigned)N) order[dst] = i;
  }
}

__device__ __forceinline__ void unpack8(uint4 u, float4& a, float4& b) {
  a.x = __uint_as_float(u.x << 16); a.y = __uint_as_float(u.x & 0xFFFF0000u);
  a.z = __uint_as_float(u.y << 16); a.w = __uint_as_float(u.y & 0xFFFF0000u);
  b.x = __uint_as_float(u.z << 16); b.y = __uint_as_float(u.z & 0xFFFF0000u);
  b.z = __uint_as_float(u.w << 16); b.w = __uint_as_float(u.w & 0xFFFF0000u);
}

// ---- fused hop: 8 lanes/node, 32 nodes/block, 4-wide chunked gather pipeline.
// Chunk: int4 packed read (prefetched), 4 row gathers + 4 U/V sets in flight,
// then 4 independent dot/shfl/exp/acc. Tail edges masked via wgt=0. ----
template <bool IN_EXT, bool OUT_EXT>
__global__ __launch_bounds__(256) void hop_kernel(
    const void* __restrict__ emb_in_v, void* __restrict__ emb_out_v,
    const int* __restrict__ cnt, const int* __restrict__ packed,
    const float* __restrict__ Ug, const float* __restrict__ Vg,
    const float* __restrict__ cg, const int* __restrict__ order,
    const void* __restrict__ ent_det, int N, int Rc) {
  int isbf = 1;
  if (IN_EXT || OUT_EXT) isbf = wave_isbf(ent_det);
  const int l = threadIdx.x & 7;
  const int slot = blockIdx.x * 32 + (threadIdx.x >> 3);
  if (slot >= N) return;
  const int n = order[slot];

  auto loadRow = [&](int row, float4& a, float4& b) {
    if (IN_EXT && !isbf) {
      const float4* q = (const float4*)((const float*)emb_in_v + (size_t)row * C);
      a = q[2 * l]; b = q[2 * l + 1];
    } else {
      uint4 u = ((const uint4*)emb_in_v)[(size_t)row * 8 + l];
      unpack8(u, a, b);
    }
  };

  const int start = n * CAP;
  int deg = cnt[n];
  if (deg > CAP) deg = CAP;
  if (deg < 0) deg = 0;

  float4 enA, enB;
  loadRow(n, enA, enB);

  float sum = 0.f;
  float4 accA = {0.f, 0.f, 0.f, 0.f}, accB = {0.f, 0.f, 0.f, 0.f};

  int4 pk = (deg > 0) ? *(const int4*)&packed[start] : make_int4(0, 0, 0, 0);
  for (int j0 = 0; j0 < deg; j0 += 4) {
    const int4 cur = pk;
    if (j0 + 4 < deg) pk = *(const int4*)&packed[start + j0 + 4];

    int tt[4], rr[4];
    tt[0] = cur.x & 0xFFFFF; rr[0] = (int)((unsigned)cur.x >> 20);
    tt[1] = cur.y & 0xFFFFF; rr[1] = (int)((unsigned)cur.y >> 20);
    tt[2] = cur.z & 0xFFFFF; rr[2] = (int)((unsigned)cur.z >> 20);
    tt[3] = cur.w & 0xFFFFF; rr[3] = (int)((unsigned)cur.w >> 20);
#pragma unroll
    for (int k = 0; k < 4; ++k) {
      if (tt[k] >= N) tt[k] = 0;      // poison-tolerant (stale slots masked below)
      if (rr[k] >= Rc) rr[k] = 0;
    }
    float4 eA[4], eB[4];
#pragma unroll
    for (int k = 0; k < 4; ++k) loadRow(tt[k], eA[k], eB[k]);
    float4 uA[4], uB[4], vA[4], vB[4];
    float cbv[4];
#pragma unroll
    for (int k = 0; k < 4; ++k) {
      const float4* uq = (const float4*)&Ug[rr[k] * C + l * 8];
      const float4* vq = (const float4*)&Vg[rr[k] * C + l * 8];
      uA[k] = uq[0]; uB[k] = uq[1];
      vA[k] = vq[0]; vB[k] = vq[1];
      cbv[k] = cg[rr[k]];
    }
#pragma unroll
    for (int k = 0; k < 4; ++k) {
      float p = uA[k].x * enA.x + uA[k].y * enA.y + uA[k].z * enA.z + uA[k].w * enA.w
              + uB[k].x * enB.x + uB[k].y * enB.y + uB[k].z * enB.z + uB[k].w * enB.w
              + vA[k].x * eA[k].x + vA[k].y * eA[k].y + vA[k].z * eA[k].z + vA[k].w * eA[k].w
              + vB[k].x * eB[k].x + vB[k].y * eB[k].y + vB[k].z * eB[k].z + vB[k].w * eB[k].w;
      p += __shfl_xor(p, 1); p += __shfl_xor(p, 2); p += __shfl_xor(p, 4);
      float s = p + cbv[k];
      s = s > 0.f ? s : LEAKY * s;
      const float wgt = (j0 + k < deg) ? __expf(fminf(s, 50.f)) : 0.f;
      sum += wgt;
      accA.x += wgt * eA[k].x; accA.y += wgt * eA[k].y;
      accA.z += wgt * eA[k].z; accA.w += wgt * eA[k].w;
      accB.x += wgt * eB[k].x; accB.y += wgt * eB[k].y;
      accB.z += wgt * eB[k].z; accB.w += wgt * eB[k].w;
    }
  }

  const float inv = (deg > 0) ? 1.0f / sum : 0.f;
  float4 oA, oB;
  oA.x = accA.x * inv + enA.x; oA.y = accA.y * inv + enA.y;
  oA.z = accA.z * inv + enA.z; oA.w = accA.w * inv + enA.w;
  oB.x = accB.x * inv + enB.x; oB.y = accB.y * inv + enB.y;
  oB.z = accB.z * inv + enB.z; oB.w = accB.w * inv + enB.w;

  float ss = oA.x * oA.x + oA.y * oA.y + oA.z * oA.z + oA.w * oA.w
           + oB.x * oB.x + oB.y * oB.y + oB.z * oB.z + oB.w * oB.w;
  ss += __shfl_xor(ss, 1); ss += __shfl_xor(ss, 2); ss += __shfl_xor(ss, 4);
  const float sc = 1.0f / fmaxf(sqrtf(ss), 1e-12f);
  oA.x *= sc; oA.y *= sc; oA.z *= sc; oA.w *= sc;
  oB.x *= sc; oB.y *= sc; oB.z *= sc; oB.w *= sc;

  if (OUT_EXT && !isbf) {
    float4* q = (float4*)((float*)emb_out_v + (size_t)n * C);
    q[2 * l] = oA; q[2 * l + 1] = oB;
  } else {
    uint4 u;
    u.x = (unsigned)f2bf(oA.x) | ((unsigned)f2bf(oA.y) << 16);
    u.y = (unsigned)f2bf(oA.z) | ((unsigned)f2bf(oA.w) << 16);
    u.z = (unsigned)f2bf(oB.x) | ((unsigned)f2bf(oB.y) << 16);
    u.w = (unsigned)f2bf(oB.z) | ((unsigned)f2bf(oB.w) << 16);
    ((uint4*)emb_out_v)[(size_t)n * 8 + l] = u;
  }
}

extern "C" void kernel_launch(void* const* d_in, const int* in_sizes, int n_in,
                              void* d_out, int out_size, void* d_ws, size_t ws_size,
                              hipStream_t stream) {
  const void* ent  = d_in[0];
  const void* rel  = d_in[1];
  const void* fcw  = d_in[2];
  const void* fcb  = d_in[3];
  const int* eidx  = (const int*)d_in[4];
  const int* etype = (const int*)d_in[5];

  const int N  = in_sizes[0] / C;
  const int R0 = in_sizes[1] / C;
  const int Rc = R0 < RMAX ? R0 : RMAX;
  const int E  = in_sizes[5];
  const int nbN = (N + 1023) / 1024;
  (void)n_in; (void)out_size;

  // coarse-bucket geometry: nbuck <= 256
  int shift = 9;
  while ((((N - 1) >> shift) + 1) > 256) shift++;
  const int nbuck = ((N - 1) >> shift) + 1;
  int bcap = (E + nbuck - 1) / nbuck;
  bcap += bcap / 4 + 256;

  char* ws = (char*)d_ws;
  size_t off = 0;
  auto alloc = [&](size_t bytes) -> void* {
    void* p = ws + off;
    off = (off + bytes + 255) & ~(size_t)255;
    return p;
  };
  // contiguous zero region: cnt[N] + hist[65*16] + bincur[65*16] + bcnt[256*16] (padded)
  int*   cnt    = (int*)alloc(((size_t)N + 1040 + 1040 + 4096 + 64) * 4);
  int*   hist   = cnt + N;
  int*   bincur = hist + 1040;
  int*   bcnt   = bincur + 1040;
  float* U      = (float*)alloc((size_t)Rc * C * 4);
  float* V      = (float*)alloc((size_t)Rc * C * 4);
  float* cv     = (float*)alloc((size_t)Rc * 4);
  int*   order  = (int*)alloc((size_t)N * 4);
  int*   packed = (int*)alloc((size_t)N * CAP * 4);
  const size_t emb0B   = (size_t)N * C * 2;
  const size_t bucketB = (size_t)nbuck * bcap * 8;
  const size_t midB    = (size_t)N * C * 2;
  const size_t base    = off;
  const size_t align = 256;
  const bool tier2 = base + ((emb0B > bucketB ? emb0B : bucketB) + align) + (midB + align) <= ws_size;
  const bool tier1 = base + (emb0B + align) + (midB + align) <= ws_size;

  void* unionbuf = alloc(tier2 ? (emb0B > bucketB ? emb0B : bucketB)
                                : (tier1 ? emb0B : 0));
  unsigned short* mid = (unsigned short*)alloc(midB);
  unsigned short* emb0 = (unsigned short*)unionbuf;
  int2* bbuf = (int2*)unionbuf;

  hipMemsetAsync(cnt, 0, ((size_t)N + 1040 + 1040 + 4096 + 64) * 4, stream);
  uvc_kernel<<<Rc, 128, 0, stream>>>(rel, fcw, fcb, U, V, cv);

  if (tier2) {
    fillA_kernel<<<(E + 1023) / 1024, 256, 0, stream>>>(eidx, etype, bcnt, bbuf,
                                                        E, N, Rc, shift, nbuck, bcap);
    fillB_kernel<<<nbuck * 4, 256, 0, stream>>>(bcnt, bbuf, cnt, packed, N, bcap);
  } else {
    fillb_kernel<<<(E + 1023) / 1024, 256, 0, stream>>>(eidx, etype, cnt, packed, E, N, Rc);
  }
  histo_kernel<<<nbN, 1024, 0, stream>>>(cnt, hist, N);
  order_kernel<<<nbN, 1024, 0, stream>>>(cnt, hist, bincur, order, N);

  const int hb = (N + 31) / 32;
  if (tier1 || tier2) {
    const int n8 = N * C / 8;
    conv_kernel<<<(n8 + 255) / 256, 256, 0, stream>>>(ent, (unsigned*)emb0, n8);
    hop_kernel<false, false><<<hb, 256, 0, stream>>>(emb0, mid, cnt, packed, U, V, cv, order, ent, N, Rc);
  } else {
    hop_kernel<true,  false><<<hb, 256, 0, stream>>>(ent, mid, cnt, packed, U, V, cv, order, ent, N, Rc);
  }
  hop_kernel<false, true ><<<hb, 256, 0, stream>>>(mid, d_out, cnt, packed, U, V, cv, order, ent, N, Rc);
}

// Round 12
// 238.097 us; speedup vs baseline: 1.0217x; 1.0217x over previous
//
#include <hip/hip_runtime.h>

#define C 64
#define RMAX 50
#define LEAKY 0.2f
#define CAP 48   // bucket slots per head; 48*4B=192B (16B-aligned for int4 reads)

__device__ __forceinline__ float bf2f(unsigned short u) {
  return __uint_as_float(((unsigned)u) << 16);
}
__device__ __forceinline__ unsigned short f2bf(float x) {
  unsigned u = __float_as_uint(x);
  return (unsigned short)((u + 0x7FFFu + ((u >> 16) & 1u)) >> 16);  // RNE
}

// ---- in-wave dtype self-detection ----
__device__ __forceinline__ int wave_isbf(const void* ent) {
  const unsigned* w = (const unsigned*)ent;
  const int lane = threadIdx.x & 63;
  int ok = 0;
#pragma unroll
  for (int i = 0; i < 4; ++i) {
    unsigned lo = w[lane + 64 * i] & 0xFFFFu;
    float a = fabsf(__uint_as_float(lo << 16));
    ok += (lo == 0u || (a >= 1e-9f && a <= 1e9f)) ? 1 : 0;
  }
#pragma unroll
  for (int d = 1; d < 64; d <<= 1) ok += __shfl_xor(ok, d, 64);
  return ok >= 224;
}
__device__ __forceinline__ int wave_is64(const int* p) {
  const int lane = threadIdx.x & 63;
  int z = (p[2 * lane + 1] == 0) ? 1 : 0;
#pragma unroll
  for (int d = 1; d < 64; d <<= 1) z += __shfl_xor(z, d, 64);
  return z >= 62;
}
__device__ __forceinline__ float loadF(const void* p, int i, int isbf) {
  return isbf ? bf2f(((const unsigned short*)p)[i]) : ((const float*)p)[i];
}

// ---- precompute U[r]=W1^T rel_r, V[r]=W2^T rel_r, c[r]=rel_r . b ----
__global__ void uvc_kernel(const void* __restrict__ rel,
                           const void* __restrict__ fcw,
                           const void* __restrict__ fcb,
                           float* __restrict__ U, float* __restrict__ V,
                           float* __restrict__ cvec) {
  const int isbf = wave_isbf(rel);
  const int r = blockIdx.x;
  const int i = threadIdx.x;  // 0..127
  float acc = 0.f;
  for (int o = 0; o < C; ++o)
    acc += loadF(rel, r * C + o, isbf) * loadF(fcw, o * (2 * C) + i, isbf);
  if (i < C) U[r * C + i] = acc;
  else       V[r * C + (i - C)] = acc;
  if (i < C) {
    float p = loadF(rel, r * C + i, isbf) * loadF(fcb, i, isbf);
#pragma unroll
    for (int d = 1; d < 64; d <<= 1) p += __shfl_xor(p, d, 64);
    if (i == 0) cvec[r] = p;
  }
}

// ---- ent -> bf16 canonical copy (runs AFTER fillB: bbuf dead, union safe) ----
__global__ void conv_kernel(const void* __restrict__ ent, unsigned* __restrict__ dst,
                            int n8) {
  const int isbf = wave_isbf(ent);
  int i = blockIdx.x * blockDim.x + threadIdx.x;
  if (i >= n8) return;
  uint4 o;
  if (isbf) {
    o = ((const uint4*)ent)[i];
  } else {
    const float4* q = (const float4*)ent;
    float4 a = q[2 * i], b = q[2 * i + 1];
    o.x = (unsigned)f2bf(a.x) | ((unsigned)f2bf(a.y) << 16);
    o.y = (unsigned)f2bf(a.z) | ((unsigned)f2bf(a.w) << 16);
    o.z = (unsigned)f2bf(b.x) | ((unsigned)f2bf(b.y) << 16);
    o.w = (unsigned)f2bf(b.z) | ((unsigned)f2bf(b.w) << 16);
  }
  ((uint4*)dst)[i] = o;
}

// ---- direct bucket fill (fallback tier) ----
__global__ void fillb_kernel(const int* __restrict__ eidx, const int* __restrict__ etype,
                             int* __restrict__ cnt, int* __restrict__ packed,
                             int E, int N, int Rc) {
  const int is64 = wave_is64(eidx);
  const int et64 = wave_is64(etype);
  const int base = (blockIdx.x * blockDim.x + threadIdx.x) * 4;
  int h[4], t[4], r[4];
#pragma unroll
  for (int k = 0; k < 4; ++k) {
    const int e = base + k;
    if (e < E) {
      h[k] = is64 ? eidx[2 * e] : eidx[e];
      t[k] = is64 ? eidx[2 * E + 2 * e] : eidx[E + e];
      r[k] = et64 ? etype[2 * e] : etype[e];
    }
  }
  int pos[4];
#pragma unroll
  for (int k = 0; k < 4; ++k) {
    const int e = base + k;
    if (e < E) {
      if ((unsigned)h[k] >= (unsigned)N) h[k] = 0;
      pos[k] = atomicAdd(&cnt[h[k]], 1);
    }
  }
#pragma unroll
  for (int k = 0; k < 4; ++k) {
    const int e = base + k;
    if (e < E && pos[k] < CAP) {
      int tt = t[k]; if ((unsigned)tt >= (unsigned)N) tt = 0;
      int rr = r[k]; if ((unsigned)rr >= (unsigned)Rc) rr = 0;
      packed[h[k] * CAP + pos[k]] = tt | (rr << 20);
    }
  }
}

// ---- fill pass A: coarse-bucket scatter. PACK4: 4B entry (h_lo<<23|r<<17|t),
// valid when N<=2^17 && Rc<=64 && shift==9. bcnt padded to 64B lines. ----
template <bool PACK4>
__global__ void fillA_kernel(const int* __restrict__ eidx, const int* __restrict__ etype,
                             int* __restrict__ bcnt, int* __restrict__ bbuf,
                             int E, int N, int Rc, int shift, int nbuck, int bcap) {
  __shared__ int lh[256];
  __shared__ int gbase[256];
  const int is64 = wave_is64(eidx);
  const int et64 = wave_is64(etype);
  const int tid = threadIdx.x;
  if (tid < 256) lh[tid] = 0;
  const int eBase = blockIdx.x * 1024;
  int h[4], tr[4], bk[4], lp[4], ok[4];
  __syncthreads();
#pragma unroll
  for (int k = 0; k < 4; ++k) {
    const int e = eBase + k * 256 + tid;
    ok[k] = (e < E);
    if (ok[k]) {
      int hh = is64 ? eidx[2 * e] : eidx[e];
      int tt = is64 ? eidx[2 * E + 2 * e] : eidx[E + e];
      int rr = et64 ? etype[2 * e] : etype[e];
      if ((unsigned)hh >= (unsigned)N) hh = 0;
      if ((unsigned)tt >= (unsigned)N) tt = 0;
      if ((unsigned)rr >= (unsigned)Rc) rr = 0;
      h[k] = hh;
      if (PACK4) tr[k] = ((hh & 511) << 23) | (rr << 17) | tt;
      else       tr[k] = tt | (rr << 20);
      bk[k] = hh >> shift;
      lp[k] = atomicAdd(&lh[bk[k]], 1);
    }
  }
  __syncthreads();
  if (tid < nbuck) gbase[tid] = lh[tid] ? atomicAdd(&bcnt[tid * 16], lh[tid]) : 0;
  __syncthreads();
#pragma unroll
  for (int k = 0; k < 4; ++k) {
    if (ok[k]) {
      int posb = gbase[bk[k]] + lp[k];
      if (posb < bcap) {
        if (PACK4) bbuf[(size_t)bk[k] * bcap + posb] = tr[k];
        else ((int2*)bbuf)[(size_t)bk[k] * bcap + posb] = make_int2(h[k], tr[k]);
      }
    }
  }
}

// ---- fill pass B: ONE block per bucket (cnt/packed region stays XCD-L2-local) ----
template <bool PACK4>
__global__ void fillB_kernel(const int* __restrict__ bcnt, const int* __restrict__ bbuf,
                             int* __restrict__ cnt, int* __restrict__ packed,
                             int N, int bcap, int shift) {
  const int b = blockIdx.x;
  int bc = bcnt[b * 16]; if (bc > bcap) bc = bcap;
  for (int k = threadIdx.x; k < bc; k += blockDim.x) {
    int h, pk;
    if (PACK4) {
      unsigned w = (unsigned)bbuf[(size_t)b * bcap + k];
      h = (b << shift) | (int)(w >> 23);
      int t = (int)(w & 0x1FFFFu);
      int r = (int)((w >> 17) & 63u);
      pk = t | (r << 20);
    } else {
      int2 e = ((const int2*)bbuf)[(size_t)b * bcap + k];
      h = e.x; pk = e.y;
    }
    if ((unsigned)h >= (unsigned)N) h = 0;
    int pos = atomicAdd(&cnt[h], 1);
    if (pos < CAP) packed[h * CAP + pos] = pk;
  }
}

// ---- degree histogram over cnt (hist padded: bin k at hist[k*16]) ----
__global__ void histo_kernel(const int* __restrict__ cnt, int* __restrict__ hist, int N) {
  __shared__ int histS[65];
  const int tid = threadIdx.x;
  for (int k = tid; k < 65; k += 1024) histS[k] = 0;
  __syncthreads();
  const int i = blockIdx.x * 1024 + tid;
  if (i < N) {
    int b = cnt[i]; if (b > 64) b = 64;
    atomicAdd(&histS[b], 1);
  }
  __syncthreads();
  for (int k = tid; k < 65; k += 1024)
    if (histS[k]) atomicAdd(&hist[k * 16], histS[k]);
}

// ---- degree-sorted order, DESCENDING (LPT) ----
__global__ void order_kernel(const int* __restrict__ cnt, const int* __restrict__ hist,
                             int* __restrict__ bincur, int* __restrict__ order, int N) {
  __shared__ int binstart[66];
  __shared__ int lh[65];
  __shared__ int lbase[65];
  const int tid = threadIdx.x;
  for (int k = tid; k < 65; k += 1024) { binstart[k] = hist[k * 16]; lh[k] = 0; }
  __syncthreads();
  if (tid == 0) {
    int run = 0;
    for (int k = 64; k >= 0; --k) { int t = binstart[k]; binstart[k] = run; run += t; }
    binstart[65] = run;
  }
  __syncthreads();
  const int i = blockIdx.x * 1024 + tid;
  int b = 0, lpos = 0;
  if (i < N) {
    b = cnt[i]; if (b > 64) b = 64;
    lpos = atomicAdd(&lh[b], 1);
  }
  __syncthreads();
  if (tid < 65) lbase[tid] = lh[tid] ? atomicAdd(&bincur[tid * 16], lh[tid]) : 0;
  __syncthreads();
  if (i < N) {
    int dst = binstart[b] + lbase[b] + lpos;
    if ((unsigned)dst < (unsigned)N) order[dst] = i;
  }
}

__device__ __forceinline__ void unpack8(uint4 u, float4& a, float4& b) {
  a.x = __uint_as_float(u.x << 16); a.y = __uint_as_float(u.x & 0xFFFF0000u);
  a.z = __uint_as_float(u.y << 16); a.w = __uint_as_float(u.y & 0xFFFF0000u);
  b.x = __uint_as_float(u.z << 16); b.y = __uint_as_float(u.z & 0xFFFF0000u);
  b.z = __uint_as_float(u.w << 16); b.w = __uint_as_float(u.w & 0xFFFF0000u);
}

// ---- fused hop: 8 lanes/node, 32 nodes/block, 4-wide chunked gather pipeline ----
template <bool IN_EXT, bool OUT_EXT>
__global__ __launch_bounds__(256) void hop_kernel(
    const void* __restrict__ emb_in_v, void* __restrict__ emb_out_v,
    const int* __restrict__ cnt, const int* __restrict__ packed,
    const float* __restrict__ Ug, const float* __restrict__ Vg,
    const float* __restrict__ cg, const int* __restrict__ order,
    const void* __restrict__ ent_det, int N, int Rc) {
  int isbf = 1;
  if (IN_EXT || OUT_EXT) isbf = wave_isbf(ent_det);
  const int l = threadIdx.x & 7;
  const int slot = blockIdx.x * 32 + (threadIdx.x >> 3);
  if (slot >= N) return;
  const int n = order[slot];

  auto loadRow = [&](int row, float4& a, float4& b) {
    if (IN_EXT && !isbf) {
      const float4* q = (const float4*)((const float*)emb_in_v + (size_t)row * C);
      a = q[2 * l]; b = q[2 * l + 1];
    } else {
      uint4 u = ((const uint4*)emb_in_v)[(size_t)row * 8 + l];
      unpack8(u, a, b);
    }
  };

  const int start = n * CAP;
  int deg = cnt[n];
  if (deg > CAP) deg = CAP;
  if (deg < 0) deg = 0;

  float4 enA, enB;
  loadRow(n, enA, enB);

  float sum = 0.f;
  float4 accA = {0.f, 0.f, 0.f, 0.f}, accB = {0.f, 0.f, 0.f, 0.f};

  int4 pk = (deg > 0) ? *(const int4*)&packed[start] : make_int4(0, 0, 0, 0);
  for (int j0 = 0; j0 < deg; j0 += 4) {
    const int4 cur = pk;
    if (j0 + 4 < deg) pk = *(const int4*)&packed[start + j0 + 4];

    int tt[4], rr[4];
    tt[0] = cur.x & 0xFFFFF; rr[0] = (int)((unsigned)cur.x >> 20);
    tt[1] = cur.y & 0xFFFFF; rr[1] = (int)((unsigned)cur.y >> 20);
    tt[2] = cur.z & 0xFFFFF; rr[2] = (int)((unsigned)cur.z >> 20);
    tt[3] = cur.w & 0xFFFFF; rr[3] = (int)((unsigned)cur.w >> 20);
#pragma unroll
    for (int k = 0; k < 4; ++k) {
      if (tt[k] >= N) tt[k] = 0;      // poison-tolerant
      if (rr[k] >= Rc) rr[k] = 0;
    }
    float4 eA[4], eB[4];
#pragma unroll
    for (int k = 0; k < 4; ++k) loadRow(tt[k], eA[k], eB[k]);
    float4 uA[4], uB[4], vA[4], vB[4];
    float cbv[4];
#pragma unroll
    for (int k = 0; k < 4; ++k) {
      const float4* uq = (const float4*)&Ug[rr[k] * C + l * 8];
      const float4* vq = (const float4*)&Vg[rr[k] * C + l * 8];
      uA[k] = uq[0]; uB[k] = uq[1];
      vA[k] = vq[0]; vB[k] = vq[1];
      cbv[k] = cg[rr[k]];
    }
#pragma unroll
    for (int k = 0; k < 4; ++k) {
      float p = uA[k].x * enA.x + uA[k].y * enA.y + uA[k].z * enA.z + uA[k].w * enA.w
              + uB[k].x * enB.x + uB[k].y * enB.y + uB[k].z * enB.z + uB[k].w * enB.w
              + vA[k].x * eA[k].x + vA[k].y * eA[k].y + vA[k].z * eA[k].z + vA[k].w * eA[k].w
              + vB[k].x * eB[k].x + vB[k].y * eB[k].y + vB[k].z * eB[k].z + vB[k].w * eB[k].w;
      p += __shfl_xor(p, 1); p += __shfl_xor(p, 2); p += __shfl_xor(p, 4);
      float s = p + cbv[k];
      s = s > 0.f ? s : LEAKY * s;
      const float wgt = (j0 + k < deg) ? __expf(fminf(s, 50.f)) : 0.f;
      sum += wgt;
      accA.x += wgt * eA[k].x; accA.y += wgt * eA[k].y;
      accA.z += wgt * eA[k].z; accA.w += wgt * eA[k].w;
      accB.x += wgt * eB[k].x; accB.y += wgt * eB[k].y;
      accB.z += wgt * eB[k].z; accB.w += wgt * eB[k].w;
    }
  }

  const float inv = (deg > 0) ? 1.0f / sum : 0.f;
  float4 oA, oB;
  oA.x = accA.x * inv + enA.x; oA.y = accA.y * inv + enA.y;
  oA.z = accA.z * inv + enA.z; oA.w = accA.w * inv + enA.w;
  oB.x = accB.x * inv + enB.x; oB.y = accB.y * inv + enB.y;
  oB.z = accB.z * inv + enB.z; oB.w = accB.w * inv + enB.w;

  float ss = oA.x * oA.x + oA.y * oA.y + oA.z * oA.z + oA.w * oA.w
           + oB.x * oB.x + oB.y * oB.y + oB.z * oB.z + oB.w * oB.w;
  ss += __shfl_xor(ss, 1); ss += __shfl_xor(ss, 2); ss += __shfl_xor(ss, 4);
  const float sc = 1.0f / fmaxf(sqrtf(ss), 1e-12f);
  oA.x *= sc; oA.y *= sc; oA.z *= sc; oA.w *= sc;
  oB.x *= sc; oB.y *= sc; oB.z *= sc; oB.w *= sc;

  if (OUT_EXT && !isbf) {
    float4* q = (float4*)((float*)emb_out_v + (size_t)n * C);
    q[2 * l] = oA; q[2 * l + 1] = oB;
  } else {
    uint4 u;
    u.x = (unsigned)f2bf(oA.x) | ((unsigned)f2bf(oA.y) << 16);
    u.y = (unsigned)f2bf(oA.z) | ((unsigned)f2bf(oA.w) << 16);
    u.z = (unsigned)f2bf(oB.x) | ((unsigned)f2bf(oB.y) << 16);
    u.w = (unsigned)f2bf(oB.z) | ((unsigned)f2bf(oB.w) << 16);
    ((uint4*)emb_out_v)[(size_t)n * 8 + l] = u;
  }
}

extern "C" void kernel_launch(void* const* d_in, const int* in_sizes, int n_in,
                              void* d_out, int out_size, void* d_ws, size_t ws_size,
                              hipStream_t stream) {
  const void* ent  = d_in[0];
  const void* rel  = d_in[1];
  const void* fcw  = d_in[2];
  const void* fcb  = d_in[3];
  const int* eidx  = (const int*)d_in[4];
  const int* etype = (const int*)d_in[5];

  const int N  = in_sizes[0] / C;
  const int R0 = in_sizes[1] / C;
  const int Rc = R0 < RMAX ? R0 : RMAX;
  const int E  = in_sizes[5];
  const int nbN = (N + 1023) / 1024;
  (void)n_in; (void)out_size;

  // coarse-bucket geometry: nbuck <= 256
  int shift = 9;
  while ((((N - 1) >> shift) + 1) > 256) shift++;
  const int nbuck = ((N - 1) >> shift) + 1;
  int bcap = (E + nbuck - 1) / nbuck;
  bcap += bcap / 4 + 256;
  const bool pack4 = (N <= 131072) && (Rc <= 64) && (shift == 9);

  char* ws = (char*)d_ws;
  size_t off = 0;
  auto alloc = [&](size_t bytes) -> void* {
    void* p = ws + off;
    off = (off + bytes + 255) & ~(size_t)255;
    return p;
  };
  const int zwords = N + 1040 + 1040 + 4096 + 64;
  int*   cnt    = (int*)alloc((size_t)zwords * 4);
  int*   hist   = cnt + N;
  int*   bincur = hist + 1040;
  int*   bcnt   = bincur + 1040;
  float* U      = (float*)alloc((size_t)Rc * C * 4);
  float* V      = (float*)alloc((size_t)Rc * C * 4);
  float* cv     = (float*)alloc((size_t)Rc * 4);
  int*   order  = (int*)alloc((size_t)N * 4);
  int*   packed = (int*)alloc((size_t)N * CAP * 4);
  const size_t emb0B   = (size_t)N * C * 2;
  const size_t bucketB = (size_t)nbuck * bcap * (pack4 ? 4 : 8);
  const size_t midB    = (size_t)N * C * 2;
  const size_t base    = off;
  const size_t align = 256;
  const bool tier2 = base + ((emb0B > bucketB ? emb0B : bucketB) + align) + (midB + align) <= ws_size;

  // unionbuf: bbuf during fill (dead after fillB), then emb0 (conv runs AFTER fillB —
  // r11 bug: conv-first clobbered by fillA. Ordering is the union's correctness invariant.)
  void* unionbuf = alloc(tier2 ? (emb0B > bucketB ? emb0B : bucketB) : 0);
  unsigned short* mid = (unsigned short*)alloc(midB);
  unsigned short* emb0 = (unsigned short*)unionbuf;
  int* bbuf = (int*)unionbuf;

  hipMemsetAsync(cnt, 0, (size_t)zwords * 4, stream);
  uvc_kernel<<<Rc, 128, 0, stream>>>(rel, fcw, fcb, U, V, cv);

  const int hb = (N + 31) / 32;
  if (tier2) {
    if (pack4) {
      fillA_kernel<true ><<<(E + 1023) / 1024, 256, 0, stream>>>(eidx, etype, bcnt, bbuf,
                                                                 E, N, Rc, shift, nbuck, bcap);
      fillB_kernel<true ><<<nbuck, 512, 0, stream>>>(bcnt, bbuf, cnt, packed, N, bcap, shift);
    } else {
      fillA_kernel<false><<<(E + 1023) / 1024, 256, 0, stream>>>(eidx, etype, bcnt, bbuf,
                                                                 E, N, Rc, shift, nbuck, bcap);
      fillB_kernel<false><<<nbuck, 512, 0, stream>>>(bcnt, bbuf, cnt, packed, N, bcap, shift);
    }
    histo_kernel<<<nbN, 1024, 0, stream>>>(cnt, hist, N);
    order_kernel<<<nbN, 1024, 0, stream>>>(cnt, hist, bincur, order, N);
    const int n8 = N * C / 8;
    conv_kernel<<<(n8 + 255) / 256, 256, 0, stream>>>(ent, (unsigned*)emb0, n8);
    hop_kernel<false, false><<<hb, 256, 0, stream>>>(emb0, mid, cnt, packed, U, V, cv, order, ent, N, Rc);
  } else {
    fillb_kernel<<<(E + 1023) / 1024, 256, 0, stream>>>(eidx, etype, cnt, packed, E, N, Rc);
    histo_kernel<<<nbN, 1024, 0, stream>>>(cnt, hist, N);
    order_kernel<<<nbN, 1024, 0, stream>>>(cnt, hist, bincur, order, N);
    hop_kernel<true,  false><<<hb, 256, 0, stream>>>(ent, mid, cnt, packed, U, V, cv, order, ent, N, Rc);
  }
  hop_kernel<false, true ><<<hb, 256, 0, stream>>>(mid, d_out, cnt, packed, U, V, cv, order, ent, N, Rc);
}

// Round 13
// 230.748 us; speedup vs baseline: 1.0542x; 1.0319x over previous
//
#include <hip/hip_runtime.h>

#define C 64
#define RMAX 50
#define LEAKY 0.2f
#define CAP 48   // bucket slots per head; 48*4B=192B (16B-aligned for int4 reads)

typedef unsigned uvec4 __attribute__((ext_vector_type(4)));

__device__ __forceinline__ float bf2f(unsigned short u) {
  return __uint_as_float(((unsigned)u) << 16);
}
__device__ __forceinline__ unsigned short f2bf(float x) {
  unsigned u = __float_as_uint(x);
  return (unsigned short)((u + 0x7FFFu + ((u >> 16) & 1u)) >> 16);  // RNE
}

// ---- in-wave dtype self-detection ----
__device__ __forceinline__ int wave_isbf(const void* ent) {
  const unsigned* w = (const unsigned*)ent;
  const int lane = threadIdx.x & 63;
  int ok = 0;
#pragma unroll
  for (int i = 0; i < 4; ++i) {
    unsigned lo = w[lane + 64 * i] & 0xFFFFu;
    float a = fabsf(__uint_as_float(lo << 16));
    ok += (lo == 0u || (a >= 1e-9f && a <= 1e9f)) ? 1 : 0;
  }
#pragma unroll
  for (int d = 1; d < 64; d <<= 1) ok += __shfl_xor(ok, d, 64);
  return ok >= 224;
}
__device__ __forceinline__ int wave_is64(const int* p) {
  const int lane = threadIdx.x & 63;
  int z = (p[2 * lane + 1] == 0) ? 1 : 0;
#pragma unroll
  for (int d = 1; d < 64; d <<= 1) z += __shfl_xor(z, d, 64);
  return z >= 62;
}
__device__ __forceinline__ float loadF(const void* p, int i, int isbf) {
  return isbf ? bf2f(((const unsigned short*)p)[i]) : ((const float*)p)[i];
}

// ================= tier2 fused pipeline =================
// K1: fillA (+uvc in extra blocks, + zeroing of cnt/hist/bincur slice)
// bcnt pre-zeroed by tiny memset. PACK4 entry: h_lo<<23|r<<17|t.
template <bool PACK4>
__global__ void fillA_kernel(const int* __restrict__ eidx, const int* __restrict__ etype,
                             int* __restrict__ bcnt, int* __restrict__ bbuf,
                             int E, int N, int Rc, int shift, int nbuck, int bcap,
                             int faBlocks, int* __restrict__ zbase, int zwords,
                             const void* __restrict__ rel, const void* __restrict__ fcw,
                             const void* __restrict__ fcb,
                             float* __restrict__ U, float* __restrict__ V,
                             float* __restrict__ cvec) {
  const int tid = threadIdx.x;
  if (blockIdx.x >= faBlocks) {
    // ---- uvc branch (50 blocks, threads 0..127) ----
    const int r = blockIdx.x - faBlocks;
    const int isbf = wave_isbf(rel);
    if (tid < 128) {
      float acc = 0.f;
      for (int o = 0; o < C; ++o)
        acc += loadF(rel, r * C + o, isbf) * loadF(fcw, o * (2 * C) + tid, isbf);
      if (tid < C) U[r * C + tid] = acc;
      else         V[r * C + (tid - C)] = acc;
      if (tid < C) {  // threads 0..63 = wave 0 exactly
        float p = loadF(rel, r * C + tid, isbf) * loadF(fcb, tid, isbf);
#pragma unroll
        for (int d = 1; d < 64; d <<= 1) p += __shfl_xor(p, d, 64);
        if (tid == 0) cvec[r] = p;
      }
    }
    return;
  }
  // ---- zero cnt/hist/bincur (complete before fillB via kernel boundary) ----
  for (int i = blockIdx.x * 256 + tid; i < zwords; i += faBlocks * 256) zbase[i] = 0;

  __shared__ int lh[256];
  __shared__ int gbase[256];
  const int is64 = wave_is64(eidx);
  const int et64 = wave_is64(etype);
  if (tid < 256) lh[tid] = 0;
  const int eBase = blockIdx.x * 1024;
  int h[4], tr[4], bk[4], lp[4], ok[4];
  __syncthreads();
#pragma unroll
  for (int k = 0; k < 4; ++k) {
    const int e = eBase + k * 256 + tid;
    ok[k] = (e < E);
    if (ok[k]) {
      int hh = is64 ? eidx[2 * e] : eidx[e];
      int tt = is64 ? eidx[2 * E + 2 * e] : eidx[E + e];
      int rr = et64 ? etype[2 * e] : etype[e];
      if ((unsigned)hh >= (unsigned)N) hh = 0;
      if ((unsigned)tt >= (unsigned)N) tt = 0;
      if ((unsigned)rr >= (unsigned)Rc) rr = 0;
      h[k] = hh;
      if (PACK4) tr[k] = ((hh & 511) << 23) | (rr << 17) | tt;
      else       tr[k] = tt | (rr << 20);
      bk[k] = hh >> shift;
      lp[k] = atomicAdd(&lh[bk[k]], 1);
    }
  }
  __syncthreads();
  if (tid < nbuck) gbase[tid] = lh[tid] ? atomicAdd(&bcnt[tid * 16], lh[tid]) : 0;
  __syncthreads();
#pragma unroll
  for (int k = 0; k < 4; ++k) {
    if (ok[k]) {
      int posb = gbase[bk[k]] + lp[k];
      if (posb < bcap) {
        if (PACK4) bbuf[(size_t)bk[k] * bcap + posb] = tr[k];
        else ((int2*)bbuf)[(size_t)bk[k] * bcap + posb] = make_int2(h[k], tr[k]);
      }
    }
  }
}

// K2: fillB (+fused degree histogram: bucket b exclusively owns heads [b<<shift, ...))
template <bool PACK4>
__global__ void fillB_kernel(const int* __restrict__ bcnt, const int* __restrict__ bbuf,
                             int* __restrict__ cnt, int* __restrict__ packed,
                             int N, int bcap, int shift, int* __restrict__ hist) {
  __shared__ int histS[65];
  const int b = blockIdx.x;
  const int tid = threadIdx.x;
  for (int k = tid; k < 65; k += blockDim.x) histS[k] = 0;
  int bc = bcnt[b * 16]; if (bc > bcap) bc = bcap;
  for (int k = tid; k < bc; k += blockDim.x) {
    int h, pk;
    if (PACK4) {
      unsigned w = (unsigned)bbuf[(size_t)b * bcap + k];
      h = (b << shift) | (int)(w >> 23);
      int t = (int)(w & 0x1FFFFu);
      int r = (int)((w >> 17) & 63u);
      pk = t | (r << 20);
    } else {
      int2 e = ((const int2*)bbuf)[(size_t)b * bcap + k];
      h = e.x; pk = e.y;
    }
    if ((unsigned)h >= (unsigned)N) h = 0;
    int pos = atomicAdd(&cnt[h], 1);
    if (pos < CAP) packed[h * CAP + pos] = pk;
  }
  __syncthreads();   // this bucket's cnt final; histogram its own head range
  const int h0 = b << shift;
  const int h1 = min(N, (b + 1) << shift);
  for (int h = h0 + tid; h < h1; h += blockDim.x) {
    int d = cnt[h]; if (d > 64) d = 64;
    atomicAdd(&histS[d], 1);
  }
  __syncthreads();
  for (int k = tid; k < 65; k += blockDim.x)
    if (histS[k]) atomicAdd(&hist[k * 16], histS[k]);
}

// K3: conv (+fused degree-sort order scatter in the first nbOrd blocks)
__global__ void conv_order_kernel(const void* __restrict__ ent, unsigned* __restrict__ dst,
                                  int n8, const int* __restrict__ cnt,
                                  const int* __restrict__ hist, int* __restrict__ bincur,
                                  int* __restrict__ order, int N, int nbOrd) {
  __shared__ int binstart[66];
  __shared__ int lh[65];
  __shared__ int lbase[65];
  const int tid = threadIdx.x;
  if (blockIdx.x < nbOrd) {
    for (int k = tid; k < 65; k += 256) { binstart[k] = hist[k * 16]; lh[k] = 0; }
    __syncthreads();
    if (tid == 0) {  // descending scan (LPT: big-degree slots first)
      int run = 0;
      for (int k = 64; k >= 0; --k) { int t = binstart[k]; binstart[k] = run; run += t; }
      binstart[65] = run;
    }
    __syncthreads();
    const int i = blockIdx.x * 256 + tid;
    int b = 0, lpos = 0;
    if (i < N) {
      b = cnt[i]; if (b > 64) b = 64;
      lpos = atomicAdd(&lh[b], 1);
    }
    __syncthreads();
    if (tid < 65) lbase[tid] = lh[tid] ? atomicAdd(&bincur[tid * 16], lh[tid]) : 0;
    __syncthreads();
    if (i < N) {
      int dst2 = binstart[b] + lbase[b] + lpos;
      if ((unsigned)dst2 < (unsigned)N) order[dst2] = i;
    }
  }
  // ---- conv copy (all blocks) ----
  const int isbf = wave_isbf(ent);
  const int gid = blockIdx.x * 256 + tid;
  if (gid >= n8) return;
  uint4 o;
  if (isbf) {
    o = ((const uint4*)ent)[gid];
  } else {
    const float4* q = (const float4*)ent;
    float4 a = q[2 * gid], b2 = q[2 * gid + 1];
    o.x = (unsigned)f2bf(a.x) | ((unsigned)f2bf(a.y) << 16);
    o.y = (unsigned)f2bf(a.z) | ((unsigned)f2bf(a.w) << 16);
    o.z = (unsigned)f2bf(b2.x) | ((unsigned)f2bf(b2.y) << 16);
    o.w = (unsigned)f2bf(b2.z) | ((unsigned)f2bf(b2.w) << 16);
  }
  ((uint4*)dst)[gid] = o;
}

// ================= fallback tier (small ws) =================
__global__ void fillb_kernel(const int* __restrict__ eidx, const int* __restrict__ etype,
                             int* __restrict__ cnt, int* __restrict__ packed,
                             int E, int N, int Rc) {
  const int is64 = wave_is64(eidx);
  const int et64 = wave_is64(etype);
  const int base = (blockIdx.x * blockDim.x + threadIdx.x) * 4;
  int h[4], t[4], r[4];
#pragma unroll
  for (int k = 0; k < 4; ++k) {
    const int e = base + k;
    if (e < E) {
      h[k] = is64 ? eidx[2 * e] : eidx[e];
      t[k] = is64 ? eidx[2 * E + 2 * e] : eidx[E + e];
      r[k] = et64 ? etype[2 * e] : etype[e];
    }
  }
  int pos[4];
#pragma unroll
  for (int k = 0; k < 4; ++k) {
    const int e = base + k;
    if (e < E) {
      if ((unsigned)h[k] >= (unsigned)N) h[k] = 0;
      pos[k] = atomicAdd(&cnt[h[k]], 1);
    }
  }
#pragma unroll
  for (int k = 0; k < 4; ++k) {
    const int e = base + k;
    if (e < E && pos[k] < CAP) {
      int tt = t[k]; if ((unsigned)tt >= (unsigned)N) tt = 0;
      int rr = r[k]; if ((unsigned)rr >= (unsigned)Rc) rr = 0;
      packed[h[k] * CAP + pos[k]] = tt | (rr << 20);
    }
  }
}
__global__ void uvc_kernel(const void* __restrict__ rel, const void* __restrict__ fcw,
                           const void* __restrict__ fcb, float* __restrict__ U,
                           float* __restrict__ V, float* __restrict__ cvec) {
  const int isbf = wave_isbf(rel);
  const int r = blockIdx.x;
  const int i = threadIdx.x;
  float acc = 0.f;
  for (int o = 0; o < C; ++o)
    acc += loadF(rel, r * C + o, isbf) * loadF(fcw, o * (2 * C) + i, isbf);
  if (i < C) U[r * C + i] = acc;
  else       V[r * C + (i - C)] = acc;
  if (i < C) {
    float p = loadF(rel, r * C + i, isbf) * loadF(fcb, i, isbf);
#pragma unroll
    for (int d = 1; d < 64; d <<= 1) p += __shfl_xor(p, d, 64);
    if (i == 0) cvec[r] = p;
  }
}
__global__ void histo_kernel(const int* __restrict__ cnt, int* __restrict__ hist, int N) {
  __shared__ int histS[65];
  const int tid = threadIdx.x;
  for (int k = tid; k < 65; k += 1024) histS[k] = 0;
  __syncthreads();
  const int i = blockIdx.x * 1024 + tid;
  if (i < N) {
    int b = cnt[i]; if (b > 64) b = 64;
    atomicAdd(&histS[b], 1);
  }
  __syncthreads();
  for (int k = tid; k < 65; k += 1024)
    if (histS[k]) atomicAdd(&hist[k * 16], histS[k]);
}
__global__ void order_kernel(const int* __restrict__ cnt, const int* __restrict__ hist,
                             int* __restrict__ bincur, int* __restrict__ order, int N) {
  __shared__ int binstart[66];
  __shared__ int lh[65];
  __shared__ int lbase[65];
  const int tid = threadIdx.x;
  for (int k = tid; k < 65; k += 1024) { binstart[k] = hist[k * 16]; lh[k] = 0; }
  __syncthreads();
  if (tid == 0) {
    int run = 0;
    for (int k = 64; k >= 0; --k) { int t = binstart[k]; binstart[k] = run; run += t; }
    binstart[65] = run;
  }
  __syncthreads();
  const int i = blockIdx.x * 1024 + tid;
  int b = 0, lpos = 0;
  if (i < N) {
    b = cnt[i]; if (b > 64) b = 64;
    lpos = atomicAdd(&lh[b], 1);
  }
  __syncthreads();
  if (tid < 65) lbase[tid] = lh[tid] ? atomicAdd(&bincur[tid * 16], lh[tid]) : 0;
  __syncthreads();
  if (i < N) {
    int dst = binstart[b] + lbase[b] + lpos;
    if ((unsigned)dst < (unsigned)N) order[dst] = i;
  }
}

__device__ __forceinline__ void unpack8(uint4 u, float4& a, float4& b) {
  a.x = __uint_as_float(u.x << 16); a.y = __uint_as_float(u.x & 0xFFFF0000u);
  a.z = __uint_as_float(u.y << 16); a.w = __uint_as_float(u.y & 0xFFFF0000u);
  b.x = __uint_as_float(u.z << 16); b.y = __uint_as_float(u.z & 0xFFFF0000u);
  b.z = __uint_as_float(u.w << 16); b.w = __uint_as_float(u.w & 0xFFFF0000u);
}

// ---- fused hop: 8 lanes/node, 32 nodes/block, 4-wide chunked gather pipeline.
// NT: d_out written non-temporal (never re-read; keep gather table cached). ----
template <bool IN_EXT, bool OUT_EXT>
__global__ __launch_bounds__(256) void hop_kernel(
    const void* __restrict__ emb_in_v, void* __restrict__ emb_out_v,
    const int* __restrict__ cnt, const int* __restrict__ packed,
    const float* __restrict__ Ug, const float* __restrict__ Vg,
    const float* __restrict__ cg, const int* __restrict__ order,
    const void* __restrict__ ent_det, int N, int Rc) {
  int isbf = 1;
  if (IN_EXT || OUT_EXT) isbf = wave_isbf(ent_det);
  const int l = threadIdx.x & 7;
  const int slot = blockIdx.x * 32 + (threadIdx.x >> 3);
  if (slot >= N) return;
  const int n = order[slot];

  auto loadRow = [&](int row, float4& a, float4& b) {
    if (IN_EXT && !isbf) {
      const float4* q = (const float4*)((const float*)emb_in_v + (size_t)row * C);
      a = q[2 * l]; b = q[2 * l + 1];
    } else {
      uint4 u = ((const uint4*)emb_in_v)[(size_t)row * 8 + l];
      unpack8(u, a, b);
    }
  };

  const int start = n * CAP;
  int deg = cnt[n];
  if (deg > CAP) deg = CAP;
  if (deg < 0) deg = 0;

  float4 enA, enB;
  loadRow(n, enA, enB);

  float sum = 0.f;
  float4 accA = {0.f, 0.f, 0.f, 0.f}, accB = {0.f, 0.f, 0.f, 0.f};

  int4 pk = (deg > 0) ? *(const int4*)&packed[start] : make_int4(0, 0, 0, 0);
  for (int j0 = 0; j0 < deg; j0 += 4) {
    const int4 cur = pk;
    if (j0 + 4 < deg) pk = *(const int4*)&packed[start + j0 + 4];

    int tt[4], rr[4];
    tt[0] = cur.x & 0xFFFFF; rr[0] = (int)((unsigned)cur.x >> 20);
    tt[1] = cur.y & 0xFFFFF; rr[1] = (int)((unsigned)cur.y >> 20);
    tt[2] = cur.z & 0xFFFFF; rr[2] = (int)((unsigned)cur.z >> 20);
    tt[3] = cur.w & 0xFFFFF; rr[3] = (int)((unsigned)cur.w >> 20);
#pragma unroll
    for (int k = 0; k < 4; ++k) {
      if (tt[k] >= N) tt[k] = 0;      // poison-tolerant
      if (rr[k] >= Rc) rr[k] = 0;
    }
    float4 eA[4], eB[4];
#pragma unroll
    for (int k = 0; k < 4; ++k) loadRow(tt[k], eA[k], eB[k]);
    float4 uA[4], uB[4], vA[4], vB[4];
    float cbv[4];
#pragma unroll
    for (int k = 0; k < 4; ++k) {
      const float4* uq = (const float4*)&Ug[rr[k] * C + l * 8];
      const float4* vq = (const float4*)&Vg[rr[k] * C + l * 8];
      uA[k] = uq[0]; uB[k] = uq[1];
      vA[k] = vq[0]; vB[k] = vq[1];
      cbv[k] = cg[rr[k]];
    }
#pragma unroll
    for (int k = 0; k < 4; ++k) {
      float p = uA[k].x * enA.x + uA[k].y * enA.y + uA[k].z * enA.z + uA[k].w * enA.w
              + uB[k].x * enB.x + uB[k].y * enB.y + uB[k].z * enB.z + uB[k].w * enB.w
              + vA[k].x * eA[k].x + vA[k].y * eA[k].y + vA[k].z * eA[k].z + vA[k].w * eA[k].w
              + vB[k].x * eB[k].x + vB[k].y * eB[k].y + vB[k].z * eB[k].z + vB[k].w * eB[k].w;
      p += __shfl_xor(p, 1); p += __shfl_xor(p, 2); p += __shfl_xor(p, 4);
      float s = p + cbv[k];
      s = s > 0.f ? s : LEAKY * s;
      const float wgt = (j0 + k < deg) ? __expf(fminf(s, 50.f)) : 0.f;
      sum += wgt;
      accA.x += wgt * eA[k].x; accA.y += wgt * eA[k].y;
      accA.z += wgt * eA[k].z; accA.w += wgt * eA[k].w;
      accB.x += wgt * eB[k].x; accB.y += wgt * eB[k].y;
      accB.z += wgt * eB[k].z; accB.w += wgt * eB[k].w;
    }
  }

  const float inv = (deg > 0) ? 1.0f / sum : 0.f;
  float4 oA, oB;
  oA.x = accA.x * inv + enA.x; oA.y = accA.y * inv + enA.y;
  oA.z = accA.z * inv + enA.z; oA.w = accA.w * inv + enA.w;
  oB.x = accB.x * inv + enB.x; oB.y = accB.y * inv + enB.y;
  oB.z = accB.z * inv + enB.z; oB.w = accB.w * inv + enB.w;

  float ss = oA.x * oA.x + oA.y * oA.y + oA.z * oA.z + oA.w * oA.w
           + oB.x * oB.x + oB.y * oB.y + oB.z * oB.z + oB.w * oB.w;
  ss += __shfl_xor(ss, 1); ss += __shfl_xor(ss, 2); ss += __shfl_xor(ss, 4);
  const float sc = 1.0f / fmaxf(sqrtf(ss), 1e-12f);
  oA.x *= sc; oA.y *= sc; oA.z *= sc; oA.w *= sc;
  oB.x *= sc; oB.y *= sc; oB.z *= sc; oB.w *= sc;

  if (OUT_EXT && !isbf) {
    float* q = (float*)emb_out_v + (size_t)n * C + l * 8;
    uvec4 w0 = { __float_as_uint(oA.x), __float_as_uint(oA.y),
                 __float_as_uint(oA.z), __float_as_uint(oA.w) };
    uvec4 w1 = { __float_as_uint(oB.x), __float_as_uint(oB.y),
                 __float_as_uint(oB.z), __float_as_uint(oB.w) };
    __builtin_nontemporal_store(w0, (uvec4*)q);
    __builtin_nontemporal_store(w1, (uvec4*)(q + 4));
  } else {
    uvec4 u = { (unsigned)f2bf(oA.x) | ((unsigned)f2bf(oA.y) << 16),
                (unsigned)f2bf(oA.z) | ((unsigned)f2bf(oA.w) << 16),
                (unsigned)f2bf(oB.x) | ((unsigned)f2bf(oB.y) << 16),
                (unsigned)f2bf(oB.z) | ((unsigned)f2bf(oB.w) << 16) };
    uvec4* dst = (uvec4*)((unsigned short*)emb_out_v + (size_t)n * C) + l;
    if (OUT_EXT) __builtin_nontemporal_store(u, dst);
    else *dst = u;
  }
}

extern "C" void kernel_launch(void* const* d_in, const int* in_sizes, int n_in,
                              void* d_out, int out_size, void* d_ws, size_t ws_size,
                              hipStream_t stream) {
  const void* ent  = d_in[0];
  const void* rel  = d_in[1];
  const void* fcw  = d_in[2];
  const void* fcb  = d_in[3];
  const int* eidx  = (const int*)d_in[4];
  const int* etype = (const int*)d_in[5];

  const int N  = in_sizes[0] / C;
  const int R0 = in_sizes[1] / C;
  const int Rc = R0 < RMAX ? R0 : RMAX;
  const int E  = in_sizes[5];
  const int nbN = (N + 1023) / 1024;
  (void)n_in; (void)out_size;

  int shift = 9;
  while ((((N - 1) >> shift) + 1) > 256) shift++;
  const int nbuck = ((N - 1) >> shift) + 1;
  int bcap = (E + nbuck - 1) / nbuck;
  bcap += bcap / 4 + 256;
  const bool pack4 = (N <= 131072) && (Rc <= 64) && (shift == 9);

  char* ws = (char*)d_ws;
  size_t off = 0;
  auto alloc = [&](size_t bytes) -> void* {
    void* p = ws + off;
    off = (off + bytes + 255) & ~(size_t)255;
    return p;
  };
  // layout: [cnt N][hist 1040][bincur 1040] (zeroed by fillA) | [bcnt 4096+64] (tiny memset)
  const int zwords = N + 1040 + 1040;
  int*   cnt    = (int*)alloc((size_t)(zwords + 4096 + 64) * 4);
  int*   hist   = cnt + N;
  int*   bincur = hist + 1040;
  int*   bcnt   = bincur + 1040;
  float* U      = (float*)alloc((size_t)Rc * C * 4);
  float* V      = (float*)alloc((size_t)Rc * C * 4);
  float* cv     = (float*)alloc((size_t)Rc * 4);
  int*   order  = (int*)alloc((size_t)N * 4);
  int*   packed = (int*)alloc((size_t)N * CAP * 4);
  const size_t emb0B   = (size_t)N * C * 2;
  const size_t bucketB = (size_t)nbuck * bcap * (pack4 ? 4 : 8);
  const size_t midB    = (size_t)N * C * 2;
  const size_t base    = off;
  const size_t align = 256;
  const bool tier2 = base + ((emb0B > bucketB ? emb0B : bucketB) + align) + (midB + align) <= ws_size;

  // unionbuf: bbuf during fill (dead after fillB), then emb0 (conv AFTER fillB —
  // ordering is the union's correctness invariant; see r11 post-mortem)
  void* unionbuf = alloc(tier2 ? (emb0B > bucketB ? emb0B : bucketB) : 0);
  unsigned short* mid = (unsigned short*)alloc(midB);
  unsigned short* emb0 = (unsigned short*)unionbuf;
  int* bbuf = (int*)unionbuf;

  const int hb = (N + 31) / 32;
  if (tier2) {
    hipMemsetAsync(bcnt, 0, (size_t)(4096 + 64) * 4, stream);
    const int fa = (E + 1023) / 1024;
    if (pack4)
      fillA_kernel<true ><<<fa + Rc, 256, 0, stream>>>(eidx, etype, bcnt, bbuf, E, N, Rc,
                                                       shift, nbuck, bcap, fa, cnt, zwords,
                                                       rel, fcw, fcb, U, V, cv);
    else
      fillA_kernel<false><<<fa + Rc, 256, 0, stream>>>(eidx, etype, bcnt, bbuf, E, N, Rc,
                                                       shift, nbuck, bcap, fa, cnt, zwords,
                                                       rel, fcw, fcb, U, V, cv);
    if (pack4)
      fillB_kernel<true ><<<nbuck, 512, 0, stream>>>(bcnt, bbuf, cnt, packed, N, bcap, shift, hist);
    else
      fillB_kernel<false><<<nbuck, 512, 0, stream>>>(bcnt, bbuf, cnt, packed, N, bcap, shift, hist);
    const int n8 = N * C / 8;
    const int cb = (n8 + 255) / 256;
    const int nbOrd = (N + 255) / 256;   // nbOrd <= cb when C >= 8
    conv_order_kernel<<<cb, 256, 0, stream>>>(ent, (unsigned*)emb0, n8, cnt, hist,
                                              bincur, order, N, nbOrd);
    hop_kernel<false, false><<<hb, 256, 0, stream>>>(emb0, mid, cnt, packed, U, V, cv, order, ent, N, Rc);
  } else {
    hipMemsetAsync(cnt, 0, (size_t)(zwords + 4096 + 64) * 4, stream);
    uvc_kernel<<<Rc, 128, 0, stream>>>(rel, fcw, fcb, U, V, cv);
    fillb_kernel<<<(E + 1023) / 1024, 256, 0, stream>>>(eidx, etype, cnt, packed, E, N, Rc);
    histo_kernel<<<nbN, 1024, 0, stream>>>(cnt, hist, N);
    order_kernel<<<nbN, 1024, 0, stream>>>(cnt, hist, bincur, order, N);
    hop_kernel<true,  false><<<hb, 256, 0, stream>>>(ent, mid, cnt, packed, U, V, cv, order, ent, N, Rc);
  }
  hop_kernel<false, true ><<<hb, 256, 0, stream>>>(mid, d_out, cnt, packed, U, V, cv, order, ent, N, Rc);
}